// Round 4
// baseline (94.273 us; speedup 1.0000x reference)
//
#include <hip/hip_runtime.h>

// TauLoss: 1 - mean_c [ sum_{i,j} sign(y[c,i]-y[c,j]) * tanh(p[c,i]-p[c,j]) / (N*(N-1)) ]
//
// Identities:
//   tanh(d*s) = s*tanh(d), s in {-1,0,1}
//   tanh(a-b) = (ta-tb)/(1-ta*tb)   -> tanh once per element, not per pair
//   summand symmetric under i<->j   -> 2 * sum over unordered pairs (tri tiles)
//   s*val = val ^ signbit(l_i-l_j)  -> exact except y-ties (error <1e-7 on output)
//
// R3 lesson: wall stuck at 42us with VALUBusy 42% -- latency-bound, not
// issue-bound. VGPR=36 proved the compiler never built the register prefetch
// pipeline; each ds_read_b128 fed only 2 pairs (~36cyc math vs ~120cyc LDS
// latency). R4: register-tile i (IT=4, one b128 read feeds 8 pairs = ~140cyc
// math) + packed-f32 math (v_pk_* via ext_vector_type(2)).

typedef float v2f __attribute__((ext_vector_type(2)));

#define TAU_N 1024
#define TAU_C 128
#define TILE  256
#define IT    4                            // i-elements per thread (registers)
#define JSL   4                            // j-slices (256 thr = 64 i-thr x 4 slices)
#define JT    (TILE / JSL)                 // 64 j per thread
#define NTILE (TAU_N / TILE)               // 4
#define NTP   (NTILE * (NTILE + 1) / 2)    // 10 tile-pairs (ti >= tj)
#define NBLK  (TAU_C * NTP)                // 1280 blocks

__device__ __constant__ int c_TI[NTP] = {0,1,1,2,2,2,3,3,3,3};
__device__ __constant__ int c_TJ[NTP] = {0,0,1,0,1,2,0,1,2,3};

__global__ __launch_bounds__(TILE) void tau_tri_kernel(
        const float* __restrict__ pred, const float* __restrict__ y,
        float* __restrict__ out, float* __restrict__ acc_ws,
        unsigned* __restrict__ cnt_ws) {
    __shared__ __align__(16) float2 rowi[TILE];   // (tanh(p), y), i-tile
    __shared__ __align__(16) float2 rowj[TILE];   // (tanh(p), y), j-tile
    __shared__ float wsum[TILE / 64];

    const int bx   = blockIdx.x;
    const int c    = bx / NTP;
    const int tp   = bx % NTP;
    const int ti   = c_TI[tp];
    const int tj   = c_TJ[tp];
    const bool diag = (ti == tj);
    const int tid  = threadIdx.x;

    const float* p = pred + c * TAU_N;
    const float* l = y    + c * TAU_N;

    // Stage both tiles (uniform; diag tiles duplicate, which is fine).
    rowi[tid] = make_float2(tanhf(p[ti * TILE + tid]), l[ti * TILE + tid]);
    rowj[tid] = make_float2(tanhf(p[tj * TILE + tid]), l[tj * TILE + tid]);
    __syncthreads();

    // My 4 i-fragments -> registers (one-time LDS reads).
    const int lane  = tid & 63;            // i-thread within tile
    const int slice = tid >> 6;            // j-slice
    float mt[IT], ml[IT];
#pragma unroll
    for (int k = 0; k < IT; ++k) {
        float2 v = rowi[lane * IT + k];
        mt[k] = v.x; ml[k] = v.y;
    }

    // Inner loop: my 64-j slice, 2 j per b128 read, 8 pairs per read.
    const float4* rowj4 = (const float4*)rowj;
    const int jb = slice * (JT / 2);       // float4 index base
    v2f acc[IT] = {{0.f,0.f},{0.f,0.f},{0.f,0.f},{0.f,0.f}};
    const v2f one2 = {1.f, 1.f};
#pragma unroll 2
    for (int jj = 0; jj < JT / 2; ++jj) {
        float4 q = rowj4[jb + jj];         // (t_j0, y_j0, t_j1, y_j1)
        v2f t2 = {q.x, q.z};
        v2f l2 = {q.y, q.w};
#pragma unroll
        for (int k = 0; k < IT; ++k) {
            v2f mt2 = {mt[k], mt[k]};
            v2f n2  = mt2 - t2;                                    // pk_add(-)
            v2f d2  = __builtin_elementwise_fma(-mt2, t2, one2);   // pk_fma
            v2f r2  = {__builtin_amdgcn_rcpf(d2.x),
                       __builtin_amdgcn_rcpf(d2.y)};
            v2f v2  = n2 * r2;                                     // pk_mul
            v2f ld2 = (v2f){ml[k], ml[k]} - l2;                    // pk_add(-)
            unsigned sx = __float_as_uint(ld2.x) & 0x80000000u;
            unsigned sy = __float_as_uint(ld2.y) & 0x80000000u;
            v2f sv = {__uint_as_float(__float_as_uint(v2.x) ^ sx),
                      __uint_as_float(__float_as_uint(v2.y) ^ sy)};
            acc[k] += sv;                                          // pk_add
        }
    }
    float acc_s = (acc[0].x + acc[0].y) + (acc[1].x + acc[1].y)
                + (acc[2].x + acc[2].y) + (acc[3].x + acc[3].y);
    // Diag tiles cover each unordered pair twice (i==j contributes exactly 0).
    if (diag) acc_s *= 0.5f;

    // Wave reduce, cross-wave via LDS, one atomic per block.
    for (int off = 32; off >= 1; off >>= 1)
        acc_s += __shfl_down(acc_s, off, 64);
    if ((tid & 63) == 0) wsum[tid >> 6] = acc_s;
    __syncthreads();
    if (tid == 0) {
        float t = (wsum[0] + wsum[1]) + (wsum[2] + wsum[3]);
        atomicAdd(acc_ws, t);
        __threadfence();
        unsigned old = atomicAdd(cnt_ws, 1u);
        if (old == NBLK - 1) {             // last block: all adds visible
            __threadfence();
            float total = atomicAdd(acc_ws, 0.0f);
            const float scale = 2.0f / ((float)TAU_N * (float)(TAU_N - 1) * (float)TAU_C);
            out[0] = 1.0f - total * scale;
        }
    }
}

extern "C" void kernel_launch(void* const* d_in, const int* in_sizes, int n_in,
                              void* d_out, int out_size, void* d_ws, size_t ws_size,
                              hipStream_t stream) {
    const float* pred = (const float*)d_in[0];
    const float* y    = (const float*)d_in[1];
    float* out        = (float*)d_out;
    float* acc_ws     = (float*)d_ws;
    unsigned* cnt_ws  = (unsigned*)d_ws + 1;

    hipMemsetAsync(d_ws, 0, 2 * sizeof(unsigned), stream);  // zero acc + counter
    tau_tri_kernel<<<NBLK, TILE, 0, stream>>>(pred, y, out, acc_ws, cnt_ws);
}

// Round 5
// 77.097 us; speedup vs baseline: 1.2228x; 1.2228x over previous
//
#include <hip/hip_runtime.h>

// TauLoss: 1 - mean_c [ sum_{i,j} sign(y[c,i]-y[c,j]) * tanh(p[c,i]-p[c,j]) / (N*(N-1)) ]
//
// Identities:
//   tanh(d*s) = s*tanh(d), s in {-1,0,1}
//   tanh(a-b) = (ta-tb)/(1-ta*tb)   -> tanh once per element, not per pair
//   summand symmetric under i<->j   -> 2 * sum over unordered tri tile-pairs
//   s*val = val ^ signbit(l_i-l_j)  -> exact except y-ties (error <1e-7 on output)
//
// R4 lesson: issue time is only ~11.6us (VALUBusy 29% x 40us) but wall stuck at
// ~40us with OccupancyPercent 19% (~6 waves/CU vs 20 configured): 1280 short
// blocks + staging barriers + LDS latency with too few resident waves. Also the
// harness's 256MB d_ws re-poison (~40us fillBuffer) is a fixed ~53us floor on
// dur_us that kernel changes cannot touch.
//
// R5: 256 blocks x 1024 threads (1 block/CU, 16 waves/CU RESIDENT), each block
// owns half a column = 5 triangular tile-pair jobs. Whole column staged once
// (1 tanh/thread, ONE barrier), then 5 jobs of pure LDS-fed packed math.

typedef float v2f __attribute__((ext_vector_type(2)));

#define TAU_N 1024
#define TAU_C 128
#define TILE  256
#define NTILE (TAU_N / TILE)               // 4
#define NTP   (NTILE * (NTILE + 1) / 2)    // 10 tile-pairs (ti >= tj) per column
#define PBLK  256                          // physical blocks (1 per CU)
#define THR   1024                         // threads per block (16 waves)
#define JOBS  ((TAU_C * NTP) / PBLK)       // 5 tile-pair jobs per block
#define IT    4                            // i-elements per thread
#define JSL   16                           // j-slices (= waves per block)
#define JT    (TILE / JSL)                 // 16 j per thread per job

__device__ __constant__ int c_TI[NTP] = {0,1,1,2,2,2,3,3,3,3};
__device__ __constant__ int c_TJ[NTP] = {0,0,1,0,1,2,0,1,2,3};

__global__ __launch_bounds__(THR) void tau_tri_kernel(
        const float* __restrict__ pred, const float* __restrict__ y,
        float* __restrict__ out, float* __restrict__ acc_ws,
        unsigned* __restrict__ cnt_ws) {
    __shared__ __align__(16) float2 col[TAU_N];   // (tanh(p), y) whole column
    __shared__ float wsum[THR / 64];

    const int bx   = blockIdx.x;            // 0..255
    const int tid  = threadIdx.x;
    const int lane = tid & 63;              // i-thread within tile
    const int wv   = tid >> 6;              // wave id == j-slice

    // Jobs 5*bx .. 5*bx+4 all live in column c = (5*bx)/10 = bx/2.
    const int c = bx >> 1;
    const float* p = pred + c * TAU_N;
    const float* l = y    + c * TAU_N;

    // Stage the whole column once: 1 tanh per thread, 1 barrier.
    col[tid] = make_float2(tanhf(p[tid]), l[tid]);
    __syncthreads();

    const float4* col4 = (const float4*)col;   // col4[k] = (t2k, y2k, t2k+1, y2k+1)
    const v2f one2 = {1.f, 1.f};
    float acc_tot = 0.f;

#pragma unroll
    for (int q = 0; q < JOBS; ++q) {
        const int job = (bx & 1) * JOBS + q;        // 0..9 within the column
        const int ti  = c_TI[job];
        const int tj  = c_TJ[job];

        // My IT=4 i-fragments from LDS (broadcast-free small reads).
        float mt[IT], ml[IT];
#pragma unroll
        for (int k = 0; k < IT; ++k) {
            float2 v = col[ti * TILE + lane * IT + k];
            mt[k] = v.x; ml[k] = v.y;
        }

        // My 16-j slice of the j-tile: 8 b128 broadcast reads, 8 pairs each.
        const int jb = (tj * TILE + wv * JT) >> 1;  // float4 index base
        v2f acc[IT] = {{0.f,0.f},{0.f,0.f},{0.f,0.f},{0.f,0.f}};
#pragma unroll
        for (int jj = 0; jj < JT / 2; ++jj) {
            float4 qv = col4[jb + jj];              // (t_j0, y_j0, t_j1, y_j1)
            v2f t2 = {qv.x, qv.z};
            v2f l2 = {qv.y, qv.w};
#pragma unroll
            for (int k = 0; k < IT; ++k) {
                v2f mt2 = {mt[k], mt[k]};
                v2f n2  = mt2 - t2;
                v2f d2  = __builtin_elementwise_fma(-mt2, t2, one2);  // 1 - mt*tj
                v2f r2  = {__builtin_amdgcn_rcpf(d2.x),
                           __builtin_amdgcn_rcpf(d2.y)};
                v2f v2  = n2 * r2;                                    // tanh(pi-pj)
                v2f ld2 = (v2f){ml[k], ml[k]} - l2;
                unsigned sx = __float_as_uint(ld2.x) & 0x80000000u;
                unsigned sy = __float_as_uint(ld2.y) & 0x80000000u;
                acc[k] += (v2f){__uint_as_float(__float_as_uint(v2.x) ^ sx),
                                __uint_as_float(__float_as_uint(v2.y) ^ sy)};
            }
        }
        float a = (acc[0].x + acc[0].y) + (acc[1].x + acc[1].y)
                + (acc[2].x + acc[2].y) + (acc[3].x + acc[3].y);
        // Diag tiles cover each unordered pair twice (i==j contributes 0).
        acc_tot += (ti == tj) ? 0.5f * a : a;
    }

    // Wave reduce, cross-wave via LDS, one atomic per block.
    for (int off = 32; off >= 1; off >>= 1)
        acc_tot += __shfl_down(acc_tot, off, 64);
    if (lane == 0) wsum[wv] = acc_tot;
    __syncthreads();
    if (tid == 0) {
        float t = 0.f;
#pragma unroll
        for (int w = 0; w < THR / 64; ++w) t += wsum[w];
        atomicAdd(acc_ws, t);
        __threadfence();
        unsigned old = atomicAdd(cnt_ws, 1u);
        if (old == PBLK - 1) {              // last block: all adds visible
            __threadfence();
            float total = atomicAdd(acc_ws, 0.0f);
            const float scale = 2.0f / ((float)TAU_N * (float)(TAU_N - 1) * (float)TAU_C);
            out[0] = 1.0f - total * scale;
        }
    }
}

extern "C" void kernel_launch(void* const* d_in, const int* in_sizes, int n_in,
                              void* d_out, int out_size, void* d_ws, size_t ws_size,
                              hipStream_t stream) {
    const float* pred = (const float*)d_in[0];
    const float* y    = (const float*)d_in[1];
    float* out        = (float*)d_out;
    float* acc_ws     = (float*)d_ws;
    unsigned* cnt_ws  = (unsigned*)d_ws + 1;

    hipMemsetAsync(d_ws, 0, 2 * sizeof(unsigned), stream);  // zero acc + counter
    tau_tri_kernel<<<PBLK, THR, 0, stream>>>(pred, y, out, acc_ws, cnt_ws);
}